// Round 11
// baseline (2098.323 us; speedup 1.0000x reference)
//
#include <hip/hip_runtime.h>
#include <cmath>

// ---------------- problem constants ----------------
#define S_   512
#define Z_   514            // SD + H
#define WUC  516            // WU_w cols: [x(2) | u(2) | h(512)]

// output float offsets
#define OUT_ZF   67371008   // B*S*Z
#define OUT_CZF  67502592   // + B*Z
#define OUT_COEF 67634176   // + B*Z

// ---------------- workspace layout ----------------
// img: [slot(4)][grp(16)] x 16KB f16 image [16 rows][512 units]; 1MB total.
// memset 0xFF at launch = f16 NaN sentinel (h is always finite).
#define IMG_BYTES 16384

// dynamic LDS: cscr [kq8][row16][unit 33-pad][gate4] f32 (67584 B) + dscr (2048 B)
#define CSCR_FLOATS 16896
#define SMEM_BYTES  69632
#define CI(kq, row, unit) ((((kq) * 16 + (row)) * 33 + (unit)) * 4)
#define DI(kq, row)       (CSCR_FLOATS + ((kq) * 16 + (row)) * 4)

typedef __attribute__((ext_vector_type(4))) float f32x4;
typedef __attribute__((ext_vector_type(4))) unsigned u32x4;
typedef __attribute__((ext_vector_type(8))) _Float16 f16x8;

__device__ __forceinline__ f32x4 MF16(f16x8 a, f16x8 b, f32x4 c) {
  return __builtin_amdgcn_mfma_f32_16x16x32_f16(a, b, c, 0, 0, 0);
}
// system-scope (sc0 sc1) coherent ops — round-2/4/6/10-proven encoding
__device__ __forceinline__ u32x4 ld16c(const void* p) {
  u32x4 r;
  asm volatile("global_load_dwordx4 %0, %1, off sc0 sc1" : "=v"(r) : "v"(p));
  return r;
}
__device__ __forceinline__ void st16c(void* p, u32x4 v) {
  asm volatile("global_store_dwordx4 %0, %1, off sc0 sc1" :: "v"(p), "v"(v) : "memory");
}
// chunk ready: no dword still holds the poison pattern in its low half
// (publish stores are 16B-aligned u32x4 -> a consumer chunk is exactly one
// producer store; dword-atomicity makes each dword all-poison or all-data)
__device__ __forceinline__ bool rdy(u32x4 v) {
  unsigned b = (unsigned)((v[0] & 0xFFFFu) == 0xFFFFu) |
               (unsigned)((v[1] & 0xFFFFu) == 0xFFFFu) |
               (unsigned)((v[2] & 0xFFFFu) == 0xFFFFu) |
               (unsigned)((v[3] & 0xFFFFu) == 0xFFFFu);
  return b == 0u;
}
__device__ __forceinline__ float sigm(float x)  { return 1.f / (1.f + __expf(-x)); }
__device__ __forceinline__ float ftanh(float x) { return 2.f / (1.f + __expf(-2.f * x)) - 1.f; }

// self-validating spin on 2 chunks (base, base+64); rule-#18 fence after drain
#define SPIN2(P0, P1, BASE)                                                  \
  {                                                                          \
    bool ok0 = false, ok1 = false;                                           \
    for (;;) {                                                               \
      if (!ok0) P0 = ld16c((BASE));                                          \
      if (!ok1) P1 = ld16c((BASE) + 64);                                     \
      asm volatile("s_waitcnt vmcnt(0)" ::: "memory");                       \
      __builtin_amdgcn_sched_barrier(0);                                     \
      ok0 = rdy(P0); ok1 = rdy(P1);                                          \
      if (ok0 && ok1) break;                                                 \
      __builtin_amdgcn_s_sleep(1);                                           \
    }                                                                        \
    __builtin_amdgcn_sched_barrier(0);                                       \
  }

// grid: 256 blocks = grp(16) x u(16); block: 512 threads = 8 waves (one per K-64)
__global__ __launch_bounds__(512, 2) void lstm_persist(
    const float* __restrict__ rnn, const float* __restrict__ tau,
    const float* __restrict__ z0,  const float* __restrict__ c0,
    const float* __restrict__ wuw, const float* __restrict__ wub,
    const float* __restrict__ awp, const float* __restrict__ abp,
    const float* __restrict__ whw, const float* __restrict__ whb,
    const float* __restrict__ Amat, const float* __restrict__ Bmat,
    float* __restrict__ out, char* __restrict__ img)
{
  extern __shared__ __align__(16) float smem[];   // cscr + dscr

  const int tid  = threadIdx.x;
  const int blk  = blockIdx.x;
  const int grp  = blk & 15;        // row group -> rows [grp*16, grp*16+16)
  const int u    = blk >> 4;        // unit block -> units [u*32, u*32+32)
  const int j0   = u * 32;
  const int lane = tid & 63;
  const int kq   = tid >> 6;        // wave = K chunk of 64
  const int ln15 = lane & 15;
  const int lq   = lane >> 4;
  const int row_l = tid >> 5;       // pointwise row 0..15
  const int unit  = tid & 31;       // pointwise unit 0..31
  const int rg    = grp * 16 + row_l;  // global batch row
  const int ju    = j0 + unit;         // global unit

  // ---------------- prologue: weights -> registers (split f16) ----------------
  // wave kq: B-frags for k-range [kq*64, kq*64+64): 2 ksteps x 2 utiles x 4 gates
  f16x8 bH[2][2][4], bL[2][2][4], dH[2], dL[2];
#pragma unroll
  for (int s = 0; s < 2; ++s) {
    const int kbase = kq * 64 + s * 32 + lq * 8;
#pragma unroll
    for (int ut = 0; ut < 2; ++ut) {
#pragma unroll
      for (int n = 0; n < 4; ++n) {
        const float* wp = wuw + (size_t)(n * 512 + j0 + ut * 16 + ln15) * WUC + 4 + kbase;
        f16x8 vh, vl;
#pragma unroll
        for (int e = 0; e < 8; ++e) {
          float w = wp[e];
          _Float16 hi = (_Float16)w;
          vh[e] = hi; vl[e] = (_Float16)(w - (float)hi);
        }
        bH[s][ut][n] = vh; bL[s][ut][n] = vl;
      }
    }
    {
      f16x8 vh, vl;
#pragma unroll
      for (int e = 0; e < 8; ++e) {   // dots tile: [alpha_w ; Wh_w ; zeros]
        int k = kbase + e;
        float w = 0.f;
        if (ln15 < 2)      w = awp[ln15 * 512 + k];
        else if (ln15 < 4) w = whw[(ln15 - 2) * 512 + k];
        _Float16 hi = (_Float16)w;
        vh[e] = hi; vl[e] = (_Float16)(w - (float)hi);
      }
      dH[s] = vh; dL[s] = vl;
    }
  }
  // small params + per-thread pointwise weights (registers, not LDS)
  const float pA00 = Amat[0], pA01 = Amat[1], pA10 = Amat[2], pA11 = Amat[3];
  const float pB0 = Bmat[0], pB1 = Bmat[1];
  const float pab0 = abp[0], pab1 = abp[1], pwb0 = whb[0], pwb1 = whb[1];
  float gb_[4], gw_[4][4];
#pragma unroll
  for (int n = 0; n < 4; ++n) {
    const int r = n * 512 + ju;
    gb_[n] = wub[r];
    const float* wr = wuw + (size_t)r * WUC;
    gw_[n][0] = wr[0]; gw_[n][1] = wr[1]; gw_[n][2] = wr[2]; gw_[n][3] = wr[3];
  }
  float px0 = z0[(size_t)rg * Z_ + 0], px1 = z0[(size_t)rg * Z_ + 1];
  float c_state = c0[(size_t)rg * Z_ + 2 + ju];
  float u0_prev = 0.f, tau_prev = 0.f, hval = 0.f;
  float alc0 = 0.f, alc1 = 0.f;

  // publish z0 h-slice into slot 3 (16B packed via 3 shfl rounds)
  {
    float hv = z0[(size_t)rg * Z_ + 2 + ju];
    unsigned hz = (unsigned)__builtin_bit_cast(unsigned short, (_Float16)hv);
    unsigned v0 = hz | ((unsigned)__shfl_xor((int)hz, 1) << 16);
    unsigned v1 = (unsigned)__shfl_xor((int)v0, 2);
    unsigned v2 = (unsigned)__shfl_xor((int)v0, 4);
    unsigned v3 = (unsigned)__shfl_xor((int)v1, 4);
    if ((unit & 7) == 0) {
      u32x4 d = {v0, v1, v2, v3};
      st16c(img + (size_t)(3 * 16 + grp) * IMG_BYTES + row_l * 1024 + ju * 2, d);
    }
  }
  __syncthreads();

  const int fragbase = ln15 * 1024 + kq * 128 + lq * 16;

  // ---------------- main loop ----------------
  for (int t = 0; t < S_; ++t) {
    const float u0v = rnn[((size_t)rg * S_ + t) * 2 + 0];
    const float u1v = rnn[((size_t)rg * S_ + t) * 2 + 1];
    const float tv  = tau[(size_t)rg * S_ + t];

    // deferred harness stores — acks complete in the spin shadow
    if (t >= 1)
      __builtin_nontemporal_store(hval, out + ((size_t)rg * S_ + (t - 1)) * Z_ + 2 + ju);
    if (t >= 2 && u == 0 && unit == 0) {
      const size_t ob = ((size_t)rg * S_ + (t - 2)) * Z_;
      __builtin_nontemporal_store(px0, out + ob + 0);
      __builtin_nontemporal_store(px1, out + ob + 1);
      const size_t cb = OUT_COEF + ((size_t)rg * S_ + (t - 2)) * 2;
      __builtin_nontemporal_store(alc0, out + cb + 0);
      __builtin_nontemporal_store(alc1, out + cb + 1);
    }

    // self-validating spin on this wave's K-slice of slot (t-1)&3
    const char* baseR = img + (size_t)(((t + 3) & 3) * 16 + grp) * IMG_BYTES + fragbase;
    u32x4 A0, A1;
    SPIN2(A0, A1, baseR);

    // GEMM: 2 ksteps x (2 utiles x 4 gates + dots) x (hi+lo) = 36 MFMA
    f32x4 ac[2][4] = {{{0,0,0,0},{0,0,0,0},{0,0,0,0},{0,0,0,0}},
                      {{0,0,0,0},{0,0,0,0},{0,0,0,0},{0,0,0,0}}};
    f32x4 ad = {0, 0, 0, 0};
#pragma unroll
    for (int s = 0; s < 2; ++s) {
      f16x8 ah = __builtin_bit_cast(f16x8, (s == 0) ? A0 : A1);
#pragma unroll
      for (int ut = 0; ut < 2; ++ut) {
#pragma unroll
        for (int n = 0; n < 4; ++n) {
          ac[ut][n] = MF16(ah, bH[s][ut][n], ac[ut][n]);
          ac[ut][n] = MF16(ah, bL[s][ut][n], ac[ut][n]);
        }
      }
      ad = MF16(ah, dH[s], ad);
      ad = MF16(ah, dL[s], ad);
    }
    // cscr: gate-major f32x4 per (row, unit); 64x16B uniform over bank quads
#pragma unroll
    for (int ut = 0; ut < 2; ++ut) {
#pragma unroll
      for (int r = 0; r < 4; ++r) {
        f32x4 v = {ac[ut][0][r], ac[ut][1][r], ac[ut][2][r], ac[ut][3][r]};
        *(f32x4*)&smem[CI(kq, lq * 4 + r, ut * 16 + ln15)] = v;
      }
    }
    if (ln15 < 4) {
#pragma unroll
      for (int r = 0; r < 4; ++r)
        smem[DI(kq, lq * 4 + r) + ln15] = ad[r];
    }
    __syncthreads();   // B1

    // pointwise: 8-deep vectorized K-partial reduce
    f32x4 g = {0, 0, 0, 0}, ds = {0, 0, 0, 0};
#pragma unroll
    for (int k2 = 0; k2 < 8; ++k2) {
      g  = g  + *(const f32x4*)&smem[CI(k2, row_l, unit)];
      ds = ds + *(const f32x4*)&smem[DI(k2, row_l)];
    }
    if (t > 0) {
      const float al0 = sigm(ds[0] + pab0), al1 = sigm(ds[1] + pab1);
      const float wh0 = ds[2] + pwb0, wh1 = ds[3] + pwb1;
      const float xm0 = px0 + tau_prev * (pA00 * px0 + pA01 * px1 + pB0 * u0_prev);
      const float xm1 = px1 + tau_prev * (pA10 * px0 + pA11 * px1 + pB1 * u0_prev);
      px0 = al0 * xm0 + (1.f - al0) * wh0;
      px1 = al1 * xm1 + (1.f - al1) * wh1;
      alc0 = al0; alc1 = al1;
    }
    float g0 = g[0] + gb_[0] + px0 * gw_[0][0] + px1 * gw_[0][1] + u0v * gw_[0][2] + u1v * gw_[0][3];
    float g1 = g[1] + gb_[1] + px0 * gw_[1][0] + px1 * gw_[1][1] + u0v * gw_[1][2] + u1v * gw_[1][3];
    float g2 = g[2] + gb_[2] + px0 * gw_[2][0] + px1 * gw_[2][1] + u0v * gw_[2][2] + u1v * gw_[2][3];
    float g3 = g[3] + gb_[3] + px0 * gw_[3][0] + px1 * gw_[3][1] + u0v * gw_[3][2] + u1v * gw_[3][3];
    const float ci = sigm(g0), cf = sigm(g1), co = sigm(g3);
    c_state = cf * c_state + ci * ftanh(g2);
    hval = co * ftanh(c_state);
    u0_prev = u0v; tau_prev = tv;

    // publish h(t) -> slot t&3 (16B packed, fire-and-forget)
    {
      unsigned hz = (unsigned)__builtin_bit_cast(unsigned short, (_Float16)hval);
      unsigned v0 = hz | ((unsigned)__shfl_xor((int)hz, 1) << 16);
      unsigned v1 = (unsigned)__shfl_xor((int)v0, 2);
      unsigned v2 = (unsigned)__shfl_xor((int)v0, 4);
      unsigned v3 = (unsigned)__shfl_xor((int)v1, 4);
      if ((unit & 7) == 0) {
        u32x4 d = {v0, v1, v2, v3};
        st16c(img + (size_t)((t & 3) * 16 + grp) * IMG_BYTES + row_l * 1024 + ju * 2, d);
      }
    }
    // wave 0 re-poisons this block's slice of slot (t+2)&3 (dead h(t-2));
    // drained by wave 0's next spin vmcnt(0), ordered before t+2's publish by B1
    if (kq == 0) {
      u32x4 poison = {~0u, ~0u, ~0u, ~0u};
      st16c(img + (size_t)(((t + 2) & 3) * 16 + grp) * IMG_BYTES
                + (lane >> 2) * 1024 + j0 * 2 + (lane & 3) * 16, poison);
    }
    __syncthreads();   // B2: full drain — producer self-throttle keeping the
                       // group phase-locked (R7/R8/R9: removing it costs ~+300us)
  }

  // ---------------- tail: pending stores + alpha/x for t = 511 ----------------
  __builtin_nontemporal_store(hval, out + ((size_t)rg * S_ + 511) * Z_ + 2 + ju);
  __builtin_nontemporal_store(hval,    out + OUT_ZF  + (size_t)rg * Z_ + 2 + ju);
  __builtin_nontemporal_store(c_state, out + OUT_CZF + (size_t)rg * Z_ + 2 + ju);
  if (u == 0 && unit == 0) {
    const size_t ob = ((size_t)rg * S_ + 510) * Z_;
    __builtin_nontemporal_store(px0, out + ob + 0);
    __builtin_nontemporal_store(px1, out + ob + 1);
    const size_t cb = OUT_COEF + ((size_t)rg * S_ + 510) * 2;
    __builtin_nontemporal_store(alc0, out + cb + 0);
    __builtin_nontemporal_store(alc1, out + cb + 1);
  }

  // final alpha/Wh dots over h(511) (slot 511&3 = 3)
  {
    const char* baseR = img + (size_t)(3 * 16 + grp) * IMG_BYTES + fragbase;
    u32x4 A0, A1;
    SPIN2(A0, A1, baseR);
    f32x4 ad = {0, 0, 0, 0};
#pragma unroll
    for (int s = 0; s < 2; ++s) {
      f16x8 ah = __builtin_bit_cast(f16x8, (s == 0) ? A0 : A1);
      ad = MF16(ah, dH[s], ad);
      ad = MF16(ah, dL[s], ad);
    }
    if (ln15 < 4) {
#pragma unroll
      for (int r = 0; r < 4; ++r)
        smem[DI(kq, lq * 4 + r) + ln15] = ad[r];
    }
  }
  __syncthreads();
  {
    f32x4 ds = {0, 0, 0, 0};
#pragma unroll
    for (int k2 = 0; k2 < 8; ++k2)
      ds = ds + *(const f32x4*)&smem[DI(k2, row_l)];
    const float al0 = sigm(ds[0] + pab0), al1 = sigm(ds[1] + pab1);
    const float wh0 = ds[2] + pwb0, wh1 = ds[3] + pwb1;
    const float xm0 = px0 + tau_prev * (pA00 * px0 + pA01 * px1 + pB0 * u0_prev);
    const float xm1 = px1 + tau_prev * (pA10 * px0 + pA11 * px1 + pB1 * u0_prev);
    const float xn0 = al0 * xm0 + (1.f - al0) * wh0;
    const float xn1 = al1 * xm1 + (1.f - al1) * wh1;
    if (u == 0 && unit == 0) {
      const size_t ob = ((size_t)rg * S_ + 511) * Z_;
      __builtin_nontemporal_store(xn0, out + ob + 0);
      __builtin_nontemporal_store(xn1, out + ob + 1);
      const size_t cb = OUT_COEF + ((size_t)rg * S_ + 511) * 2;
      __builtin_nontemporal_store(al0, out + cb + 0);
      __builtin_nontemporal_store(al1, out + cb + 1);
      __builtin_nontemporal_store(xn0, out + OUT_ZF  + (size_t)rg * Z_ + 0);
      __builtin_nontemporal_store(xn1, out + OUT_ZF  + (size_t)rg * Z_ + 1);
      __builtin_nontemporal_store(c0[(size_t)rg * Z_ + 0], out + OUT_CZF + (size_t)rg * Z_ + 0);
      __builtin_nontemporal_store(c0[(size_t)rg * Z_ + 1], out + OUT_CZF + (size_t)rg * Z_ + 1);
    }
  }
}

extern "C" void kernel_launch(void* const* d_in, const int* in_sizes, int n_in,
                              void* d_out, int out_size, void* d_ws, size_t ws_size,
                              hipStream_t stream) {
  const float* rnn  = (const float*)d_in[0];
  const float* tauP = (const float*)d_in[1];
  const float* z0   = (const float*)d_in[2];
  const float* c0   = (const float*)d_in[3];
  const float* wuw  = (const float*)d_in[4];
  const float* wub  = (const float*)d_in[5];
  const float* awp  = (const float*)d_in[6];
  const float* abp  = (const float*)d_in[7];
  const float* whw  = (const float*)d_in[8];
  const float* whb  = (const float*)d_in[9];
  const float* Amat = (const float*)d_in[10];
  const float* Bmat = (const float*)d_in[11];
  float* out = (float*)d_out;
  char* img = (char*)d_ws;   // 1 MB: 4 slots x 16 grp x 16KB

  // poison all image slots (f16 NaN sentinel) every call — captured in the graph
  hipMemsetAsync(d_ws, 0xFF, 4 * 16 * IMG_BYTES, stream);
  hipFuncSetAttribute((const void*)lstm_persist,
                      hipFuncAttributeMaxDynamicSharedMemorySize, SMEM_BYTES);
  (void)in_sizes; (void)n_in; (void)out_size; (void)ws_size;

  hipLaunchKernelGGL(lstm_persist, dim3(256), dim3(512), SMEM_BYTES, stream,
                     rnn, tauP, z0, c0, wuw, wub, awp, abp, whw, whb, Amat, Bmat,
                     out, img);
}